// Round 5
// baseline (5665.185 us; speedup 1.0000x reference)
//
#include <hip/hip_runtime.h>
#include <math.h>

// DecoderLSTM greedy decode, MI355X. V=32000 H=1024 T=32 B=64.
// Logits GEMM: bf16 MFMA (16x16x32) with 3-term split (hi*hi + hi*lo + lo*hi),
// fp32 accumulate. Gates GEMM fp32 (recurrence amplifies error).
//
// R5: logits occupancy fix. R4's H-LDS staging reverted (32 barriers/block on
// L2-resident data = regression, Common-mistake #7). Logits was 1 wave/SIMD
// (grid 250 x 4 waves) with ~12 loads in flight -> latency-bound at ~2-4 TB/s.
// Now: wave = 16v (was 32v), grid 500 -> 2 waves/SIMD, 3-buffer prefetch ring
// (fully unrolled -> static indices) -> ~2x in-flight bytes. Accumulation
// order per output unchanged -> logits bitwise identical (absmax canary).
// Keep R4's gates-prolog finalize fusion (3 dispatches/step).
//
// ws float offsets:
//   pmax[500][64]@0  psum[500][64]@32768
//   h[1024][64]@65536  c[1024][64]@131072
//   part[8][4096][64]@196608 (ends 2293760)  pidx(int)[500][64]@2293760
// ushort (bf16) at float offset 2359296: Whi[32000][1024], Wlo[32000][1024],
//   Hhi[64][1024], Hlo[64][1024]

typedef short bf16x8 __attribute__((ext_vector_type(8)));
typedef float f32x4 __attribute__((ext_vector_type(4)));

constexpr int kH = 1024;
constexpr int kFH = 4096;
constexpr int kB = 64;
constexpr int kV = 32000;
constexpr int kT = 32;
constexpr int kSOS = 1;
constexpr int kEOS = 2;
constexpr int kLB = 500;  // logits blocks (64 v each)

__device__ inline unsigned short f2bf(float f) {  // RNE float->bf16
  unsigned int u = __float_as_uint(f);
  u += 0x7fffu + ((u >> 16) & 1u);
  return (unsigned short)(u >> 16);
}
__device__ inline float bf2f(unsigned short h) {
  return __uint_as_float(((unsigned int)h) << 16);
}

// ---------------------------------------------------------------- init ------
__global__ __launch_bounds__(256) void init_kernel(
    const float* __restrict__ eh, const float* __restrict__ ec,
    float* __restrict__ ws) {
  int g = blockIdx.x * 256 + threadIdx.x;  // grid 512 -> 0..131071
  float* h = ws + 65536;
  float* c = ws + 131072;
  if (g < 65536) {
    int u = g >> 6, b = g & 63;
    c[u * 64 + b] = ec[(size_t)b * kH + u];
  } else {
    int i = g - 65536;
    int u = i >> 6, b = i & 63;
    h[i] = eh[(size_t)b * kH + u];
  }
}

// ------------------------------------------------------------- W split ------
__global__ __launch_bounds__(256) void wsplit_kernel(
    const float* __restrict__ W, unsigned short* __restrict__ hi,
    unsigned short* __restrict__ lo) {
  size_t i = ((size_t)blockIdx.x * 256 + threadIdx.x) * 4;
  float4 w = *(const float4*)(W + i);
  unsigned short h0 = f2bf(w.x), h1 = f2bf(w.y), h2 = f2bf(w.z), h3 = f2bf(w.w);
  ushort4 hv = make_ushort4(h0, h1, h2, h3);
  ushort4 lv = make_ushort4(f2bf(w.x - bf2f(h0)), f2bf(w.y - bf2f(h1)),
                            f2bf(w.z - bf2f(h2)), f2bf(w.w - bf2f(h3)));
  *(ushort4*)(hi + i) = hv;
  *(ushort4*)(lo + i) = lv;
}

// --------------------------------------------------------------- gates ------
// part[s][r][b] += W[r][k] * z[k][b]. grid(64,8).
// Prolog (phase-0 blocks): reduce prev-step partials -> rowp[b]=&E[amax[b]];
// block (0,0) also writes mask[t-1]. t==0: rowp = &E[SOS]. No fences: the
// partials were written by the previous kernel (boundary = coherence).
__global__ __launch_bounds__(256) void gates_kernel(
    const float* __restrict__ Wih, const float* __restrict__ Whh,
    const float* __restrict__ E, const float* __restrict__ h,
    float* __restrict__ part, const float* __restrict__ pmax_g,
    const float* __restrict__ psum_g, const int* __restrict__ pidx_g,
    const float* __restrict__ out_prev, float* __restrict__ mask_prev, int t) {
  __shared__ __align__(16) float Wt[64 * 68];
  __shared__ __align__(16) float Zt[64 * 68];
  __shared__ const float* rowp[64];
  __shared__ float redA[4][64];
  __shared__ int redI[4][64];
  __shared__ float redS[4][64];
  const int tid = threadIdx.x;
  const int s = blockIdx.y;
  const int r0 = blockIdx.x * 64;
  const int phase = s >> 2;
  const int kc0 = (s & 3) * 256;
  const float* __restrict__ W = phase ? Whh : Wih;

  if (!phase) {
    const int b = tid & 63, kq = tid >> 6;
    if (t == 0) {
      if (tid < 64) rowp[tid] = E + (size_t)kSOS * kH;
    } else {
      float mx = -INFINITY;
      int ix = 0x7fffffff;
      for (int k = kq; k < kLB; k += 4) {
        float v = pmax_g[k * 64 + b];
        int ii = pidx_g[k * 64 + b];
        if (v > mx || (v == mx && ii < ix)) { mx = v; ix = ii; }
      }
      redA[kq][b] = mx;
      redI[kq][b] = ix;
      __syncthreads();
      if (tid < 64) {
        float M = redA[0][tid];
        int ai = redI[0][tid];
#pragma unroll
        for (int w2 = 1; w2 < 4; ++w2) {
          float v = redA[w2][tid];
          int ii = redI[w2][tid];
          if (v > M || (v == M && ii < ai)) { M = v; ai = ii; }
        }
        rowp[tid] = E + (size_t)ai * kH;
        redA[0][tid] = M;
      }
      if (blockIdx.x == 0) {  // mask[t-1] (block-uniform branch)
        __syncthreads();
        float M = redA[0][b];
        float sacc = 0.f;
        for (int k = kq; k < kLB; k += 4)
          sacc += psum_g[k * 64 + b] * expf(pmax_g[k * 64 + b] - M);
        redS[kq][b] = sacc;
        __syncthreads();
        if (tid < 64) {
          float S = redS[0][tid] + redS[1][tid] + redS[2][tid] + redS[3][tid];
          mask_prev[tid] = expf(out_prev[(size_t)tid * kV + kEOS] - M) / S;
        }
      }
    }
  }
  __syncthreads();

  const int tb4 = tid & 15;
  const int tr4 = tid >> 4;
  float acc[4][4];
#pragma unroll
  for (int i = 0; i < 4; ++i)
#pragma unroll
    for (int j = 0; j < 4; ++j) acc[i][j] = 0.f;

  for (int kc = kc0; kc < kc0 + 256; kc += 64) {
#pragma unroll
    for (int l = 0; l < 4; ++l) {
      int f4 = tid + 256 * l;
      int row = f4 >> 4;
      int c4 = f4 & 15;
      float4 w = *(const float4*)(W + (size_t)(r0 + row) * kH + kc + c4 * 4);
      float wv[4] = {w.x, w.y, w.z, w.w};
#pragma unroll
      for (int cc = 0; cc < 4; ++cc) {
        int c = (cc + c4) & 3;
        Wt[(c4 * 4 + c) * 68 + row] = wv[c];
      }
    }
    if (!phase) {  // z = E[amax[b]] rows (row-major gather, coalesced 1KB/row)
#pragma unroll
      for (int l = 0; l < 4; ++l) {
        int g = tid + 256 * l;  // 0..1023
        int zb = g >> 4, k4 = g & 15;
        f32x4 v = *(const f32x4*)(rowp[zb] + kc + k4 * 4);
#pragma unroll
        for (int j = 0; j < 4; ++j) Zt[(k4 * 4 + j) * 68 + zb] = v[j];
      }
    } else {  // z = h, [k][b] layout
#pragma unroll
      for (int l = 0; l < 4; ++l) {
        int f4 = tid + 256 * l;
        int kk = f4 >> 4;
        int b4 = f4 & 15;
        *(float4*)(&Zt[kk * 68 + b4 * 4]) =
            *(const float4*)(h + (size_t)(kc + kk) * 64 + b4 * 4);
      }
    }
    __syncthreads();
#pragma unroll
    for (int kk = 0; kk < 64; ++kk) {
      float4 a = *(const float4*)(&Wt[kk * 68 + tr4 * 4]);
      float4 zb = *(const float4*)(&Zt[kk * 68 + tb4 * 4]);
      float av[4] = {a.x, a.y, a.z, a.w};
      float zv[4] = {zb.x, zb.y, zb.z, zb.w};
#pragma unroll
      for (int i = 0; i < 4; ++i)
#pragma unroll
        for (int j = 0; j < 4; ++j) acc[i][j] += av[i] * zv[j];
    }
    __syncthreads();
  }
#pragma unroll
  for (int i = 0; i < 4; ++i) {
    float4 o = make_float4(acc[i][0], acc[i][1], acc[i][2], acc[i][3]);
    *(float4*)(&part[((size_t)s * kFH + r0 + tr4 * 4 + i) * 64 + tb4 * 4]) = o;
  }
}

// ------------------------------------------------- lstm (+ hsplit fused) ----
__global__ __launch_bounds__(256) void lstm_kernel(
    const float* __restrict__ part, const float* __restrict__ bih,
    const float* __restrict__ bhh, float* __restrict__ h,
    float* __restrict__ c, unsigned short* __restrict__ Hhi,
    unsigned short* __restrict__ Hlo) {
  int g = blockIdx.x * 256 + threadIdx.x;
  int b = g & 63, u = g >> 6;
  float gate[4];
#pragma unroll
  for (int ty = 0; ty < 4; ++ty) {
    int r = ty * kH + u;
    float acc = bih[r] + bhh[r];
#pragma unroll
    for (int s2 = 0; s2 < 8; ++s2)
      acc += part[((size_t)s2 * kFH + r) * 64 + b];
    gate[ty] = acc;
  }
  float gi = 1.f / (1.f + expf(-gate[0]));
  float gf = 1.f / (1.f + expf(-gate[1]));
  float gg = tanhf(gate[2]);
  float go = 1.f / (1.f + expf(-gate[3]));
  float cn = gf * c[g] + gi * gg;
  float hn = go * tanhf(cn);
  c[g] = cn;
  h[g] = hn;
  unsigned short hb = f2bf(hn);
  Hhi[(size_t)b * kH + u] = hb;
  Hlo[(size_t)b * kH + u] = f2bf(hn - bf2f(hb));
}

// ------------------------------------------------------- logits (MFMA) ------
// out[b][v] = sum_k W[v][k] h[k][b] + bout[v]. Block 256 thr = 4 waves;
// wave = 16v x 64b (1 v-tile); block covers 64v; grid 500 -> ~2 blocks/CU
// -> 2 waves/SIMD. 3-buffer prefetch ring, fully unrolled (static indices).
// No barriers in main loop; direct global frag loads (H is L2-resident).
struct Frag {
  bf16x8 ah, al, bh[4], bl[4];
};

__device__ inline void load_frag(Frag& f, const unsigned short* wp,
                                 const unsigned short* lp,
                                 const unsigned short* hh,
                                 const unsigned short* hl, int ko) {
  f.ah = *(const bf16x8*)(wp + ko);
  f.al = *(const bf16x8*)(lp + ko);
#pragma unroll
  for (int bt = 0; bt < 4; ++bt) {
    f.bh[bt] = *(const bf16x8*)(hh + bt * 16 * kH + ko);
    f.bl[bt] = *(const bf16x8*)(hl + bt * 16 * kH + ko);
  }
}

__device__ inline void do_mfma(const Frag& f, f32x4 acc[4]) {
#pragma unroll
  for (int bt = 0; bt < 4; ++bt) {
    acc[bt] = __builtin_amdgcn_mfma_f32_16x16x32_bf16(f.ah, f.bh[bt], acc[bt],
                                                      0, 0, 0);
    acc[bt] = __builtin_amdgcn_mfma_f32_16x16x32_bf16(f.ah, f.bl[bt], acc[bt],
                                                      0, 0, 0);
    acc[bt] = __builtin_amdgcn_mfma_f32_16x16x32_bf16(f.al, f.bh[bt], acc[bt],
                                                      0, 0, 0);
  }
}

__global__ __launch_bounds__(256) void logits_mfma_kernel(
    const unsigned short* __restrict__ Whi, const unsigned short* __restrict__ Wlo,
    const unsigned short* __restrict__ Hhi, const unsigned short* __restrict__ Hlo,
    const float* __restrict__ bout, float* __restrict__ out,
    float* __restrict__ pmax_g, float* __restrict__ psum_g,
    int* __restrict__ pidx_g) {
  const int tid = threadIdx.x;
  const int wave = tid >> 6, lane = tid & 63;
  const int m = lane & 15, q = lane >> 4;
  const int v0 = blockIdx.x * 64 + wave * 16;
  const unsigned short* wp = Whi + (size_t)(v0 + m) * kH + q * 8;
  const unsigned short* lp = Wlo + (size_t)(v0 + m) * kH + q * 8;
  const unsigned short* hh = Hhi + (size_t)m * kH + q * 8;
  const unsigned short* hl = Hlo + (size_t)m * kH + q * 8;

  f32x4 acc[4];
#pragma unroll
  for (int bt = 0; bt < 4; ++bt) acc[bt] = (f32x4){0.f, 0.f, 0.f, 0.f};

  Frag f[3];
  load_frag(f[0], wp, lp, hh, hl, 0);
  load_frag(f[1], wp, lp, hh, hl, 32);
#pragma unroll
  for (int i = 0; i < 32; ++i) {  // fully unrolled -> static f[] indices
    if (i + 2 < 32) load_frag(f[(i + 2) % 3], wp, lp, hh, hl, (i + 2) * 32);
    do_mfma(f[i % 3], acc);
  }

  // bias in-place; store logits. D layout: row(v)=q*4+reg, col(b)=lane&15.
  float4 bo = *(const float4*)(bout + v0 + q * 4);
#pragma unroll
  for (int bt = 0; bt < 4; ++bt) {
    int b = bt * 16 + m;
    f32x4 a = acc[bt];
    a[0] += bo.x; a[1] += bo.y; a[2] += bo.z; a[3] += bo.w;
    acc[bt] = a;
    float4 o = make_float4(a[0], a[1], a[2], a[3]);
    *(float4*)(out + (size_t)b * kV + v0 + q * 4) = o;
  }

  // ---- per-block softmax/argmax partials, layout [blk][64] (coalesced)
  __shared__ float lred[4][4][64];
  __shared__ int lidx[4][4][64];
  __shared__ float bbm[64];
  const int blk = blockIdx.x;

#pragma unroll
  for (int bt = 0; bt < 4; ++bt) {
    float pmv = -INFINITY;
    int piv = 0x7fffffff;
#pragma unroll
    for (int r = 0; r < 4; ++r) {
      float val = acc[bt][r];
      int v = v0 + q * 4 + r;
      if (val > pmv) { pmv = val; piv = v; }  // strict >, v ascending
    }
    lred[wave][q][bt * 16 + m] = pmv;
    lidx[wave][q][bt * 16 + m] = piv;
  }
  __syncthreads();
  if (tid < 64) {
    float bm = -INFINITY;
    int bi = 0x7fffffff;
#pragma unroll
    for (int w = 0; w < 4; ++w)  // (w,qq) ascending == v ascending
#pragma unroll
      for (int qq = 0; qq < 4; ++qq) {
        float v2 = lred[w][qq][tid];
        int i2 = lidx[w][qq][tid];
        if (v2 > bm || (v2 == bm && i2 < bi)) { bm = v2; bi = i2; }
      }
    bbm[tid] = bm;
    pmax_g[(size_t)blk * 64 + tid] = bm;
    pidx_g[(size_t)blk * 64 + tid] = bi;
  }
  __syncthreads();
#pragma unroll
  for (int bt = 0; bt < 4; ++bt) {
    float bm = bbm[bt * 16 + m];
    float s = 0.f;
#pragma unroll
    for (int r = 0; r < 4; ++r) s += expf(acc[bt][r] - bm);
    lred[wave][q][bt * 16 + m] = s;
  }
  __syncthreads();
  if (tid < 64) {
    float s = 0.f;
#pragma unroll
    for (int w = 0; w < 4; ++w)
#pragma unroll
      for (int qq = 0; qq < 4; ++qq) s += lred[w][qq][tid];
    psum_g[(size_t)blk * 64 + tid] = s;
  }
}

// --------------------------------------------- final mask (t = T-1 only) ----
__global__ __launch_bounds__(256) void final_mask_kernel(
    const float* __restrict__ pm, const float* __restrict__ ps,
    const float* __restrict__ out_t, float* __restrict__ mask) {
  __shared__ float rm[4][64];
  __shared__ float rs[4][64];
  const int tid = threadIdx.x;
  const int b = tid & 63, kq = tid >> 6;
  float mx = -INFINITY;
  for (int k = kq; k < kLB; k += 4) {
    float v = pm[k * 64 + b];
    if (v > mx) mx = v;
  }
  rm[kq][b] = mx;
  __syncthreads();
  if (tid < 64) {
    float M = fmaxf(fmaxf(rm[0][tid], rm[1][tid]), fmaxf(rm[2][tid], rm[3][tid]));
    rm[0][tid] = M;
  }
  __syncthreads();
  float M = rm[0][b];
  float s = 0.f;
  for (int k = kq; k < kLB; k += 4)
    s += ps[k * 64 + b] * expf(pm[k * 64 + b] - M);
  rs[kq][b] = s;
  __syncthreads();
  if (tid < 64) {
    float S = rs[0][tid] + rs[1][tid] + rs[2][tid] + rs[3][tid];
    mask[tid] = expf(out_t[(size_t)tid * kV + kEOS] - M) / S;
  }
}

// -------------------------------------------------------------- launch ------
extern "C" void kernel_launch(void* const* d_in, const int* in_sizes, int n_in,
                              void* d_out, int out_size, void* d_ws,
                              size_t ws_size, hipStream_t stream) {
  const float* E = (const float*)d_in[0];
  const float* Wih = (const float*)d_in[1];
  const float* Whh = (const float*)d_in[2];
  const float* bih = (const float*)d_in[3];
  const float* bhh = (const float*)d_in[4];
  const float* Wout = (const float*)d_in[5];
  const float* bout = (const float*)d_in[6];
  const float* eh = (const float*)d_in[7];
  const float* ec = (const float*)d_in[8];
  float* out = (float*)d_out;
  float* ws = (float*)d_ws;

  float* pmaxg = ws;           // [500][64]
  float* psumg = ws + 32768;   // [500][64]
  float* h = ws + 65536;
  float* c = ws + 131072;
  float* part = ws + 196608;   // 8*4096*64 floats, ends 2293760
  int* pidxg = (int*)(ws + 2293760);  // [500][64] ints, ends 2325760
  unsigned short* Whi = (unsigned short*)(ws + 2359296);
  unsigned short* Wlo = Whi + (size_t)kV * kH;
  unsigned short* Hhi = Wlo + (size_t)kV * kH;
  unsigned short* Hlo = Hhi + (size_t)kB * kH;
  float* maskbase = out + (size_t)kT * kB * kV;

  init_kernel<<<512, 256, 0, stream>>>(eh, ec, ws);
  wsplit_kernel<<<kV, 256, 0, stream>>>(Wout, Whi, Wlo);
  for (int t = 0; t < kT; ++t) {
    float* out_t = out + (size_t)t * kB * kV;
    const float* out_prev = t ? out + (size_t)(t - 1) * kB * kV : nullptr;
    float* mask_prev = t ? maskbase + (size_t)(t - 1) * kB : nullptr;
    gates_kernel<<<dim3(64, 8), 256, 0, stream>>>(
        Wih, Whh, E, h, part, pmaxg, psumg, pidxg, out_prev, mask_prev, t);
    lstm_kernel<<<256, 256, 0, stream>>>(part, bih, bhh, h, c, Hhi, Hlo);
    logits_mfma_kernel<<<kLB, 256, 0, stream>>>(Whi, Wlo, Hhi, Hlo, bout,
                                                out_t, pmaxg, psumg, pidxg);
  }
  final_mask_kernel<<<1, 256, 0, stream>>>(
      pmaxg, psumg, out + (size_t)(kT - 1) * kB * kV,
      maskbase + (size_t)(kT - 1) * kB);
}

// Round 6
// 3773.568 us; speedup vs baseline: 1.5013x; 1.5013x over previous
//
#include <hip/hip_runtime.h>
#include <math.h>

// DecoderLSTM greedy decode, MI355X. V=32000 H=1024 T=32 B=64.
// Logits GEMM: bf16 MFMA (16x16x32) with 3-term split (hi*hi + hi*lo + lo*hi),
// fp32 accumulate. Gates GEMM fp32 (recurrence amplifies error).
//
// R6: re-anchor on the R1 kernel set (2972us proven). Two audited deltas:
//  - gates-prolog finalize fusion (R4-verified): 4 -> 3 dispatches/step,
//    partials reduced consumer-side (kernel-boundary coherence, NO fences).
//  - logits: NAMED triple-buffer prefetch (f0,f1,f2; rolled 96-k loop +
//    epilogue; no arrays -> no scratch risk, rule #20). Same MFMA order ->
//    bitwise-identical logits. R5's array-ring (scratch suspect) abandoned.
//
// ws float offsets:
//   h[1024][64]@65536  c[1024][64]@131072  part[8][4096][64]@196608
//   pmax[250][64]@2293760  psum[250][64]@2310144  pidx(int)[250][64]@2326528
// ushort (bf16) at float offset 2359296: Whi[32000][1024], Wlo[32000][1024],
//   Hhi[64][1024], Hlo[64][1024]

typedef short bf16x8 __attribute__((ext_vector_type(8)));
typedef float f32x4 __attribute__((ext_vector_type(4)));

constexpr int kH = 1024;
constexpr int kFH = 4096;
constexpr int kB = 64;
constexpr int kV = 32000;
constexpr int kT = 32;
constexpr int kSOS = 1;
constexpr int kEOS = 2;
constexpr int kLB = 250;  // logits blocks (128 v each)

__device__ inline unsigned short f2bf(float f) {  // RNE float->bf16
  unsigned int u = __float_as_uint(f);
  u += 0x7fffu + ((u >> 16) & 1u);
  return (unsigned short)(u >> 16);
}
__device__ inline float bf2f(unsigned short h) {
  return __uint_as_float(((unsigned int)h) << 16);
}

// ---------------------------------------------------------------- init ------
__global__ __launch_bounds__(256) void init_kernel(
    const float* __restrict__ eh, const float* __restrict__ ec,
    float* __restrict__ ws) {
  int g = blockIdx.x * 256 + threadIdx.x;  // grid 512 -> 0..131071
  float* h = ws + 65536;
  float* c = ws + 131072;
  if (g < 65536) {
    int u = g >> 6, b = g & 63;
    c[u * 64 + b] = ec[(size_t)b * kH + u];
  } else {
    int i = g - 65536;
    int u = i >> 6, b = i & 63;
    h[i] = eh[(size_t)b * kH + u];
  }
}

// ------------------------------------------------------------- W split ------
__global__ __launch_bounds__(256) void wsplit_kernel(
    const float* __restrict__ W, unsigned short* __restrict__ hi,
    unsigned short* __restrict__ lo) {
  size_t i = ((size_t)blockIdx.x * 256 + threadIdx.x) * 4;
  float4 w = *(const float4*)(W + i);
  unsigned short h0 = f2bf(w.x), h1 = f2bf(w.y), h2 = f2bf(w.z), h3 = f2bf(w.w);
  ushort4 hv = make_ushort4(h0, h1, h2, h3);
  ushort4 lv = make_ushort4(f2bf(w.x - bf2f(h0)), f2bf(w.y - bf2f(h1)),
                            f2bf(w.z - bf2f(h2)), f2bf(w.w - bf2f(h3)));
  *(ushort4*)(hi + i) = hv;
  *(ushort4*)(lo + i) = lv;
}

// --------------------------------------------------------------- gates ------
// part[s][r][b] += W[r][k] * z[k][b]. grid(64,8).
// Prolog (phase-0 blocks): reduce prev-step partials -> rowp[b]=&E[amax[b]];
// blocks (0, 0..3) also write mask[t-1] (identical values, benign). t==0:
// rowp = &E[SOS]. No fences: partials came from the previous kernel.
__global__ __launch_bounds__(256) void gates_kernel(
    const float* __restrict__ Wih, const float* __restrict__ Whh,
    const float* __restrict__ E, const float* __restrict__ h,
    float* __restrict__ part, const float* __restrict__ pmax_g,
    const float* __restrict__ psum_g, const int* __restrict__ pidx_g,
    const float* __restrict__ out_prev, float* __restrict__ mask_prev, int t) {
  __shared__ __align__(16) float Wt[64 * 68];
  __shared__ __align__(16) float Zt[64 * 68];
  __shared__ const float* rowp[64];
  __shared__ float redA[4][64];
  __shared__ int redI[4][64];
  __shared__ float redS[4][64];
  const int tid = threadIdx.x;
  const int s = blockIdx.y;
  const int r0 = blockIdx.x * 64;
  const int phase = s >> 2;
  const int kc0 = (s & 3) * 256;
  const float* __restrict__ W = phase ? Whh : Wih;

  if (!phase) {
    const int b = tid & 63, kq = tid >> 6;
    if (t == 0) {
      if (tid < 64) rowp[tid] = E + (size_t)kSOS * kH;
    } else {
      float mx = -INFINITY;
      int ix = 0x7fffffff;
      for (int k = kq; k < kLB; k += 4) {
        float v = pmax_g[k * 64 + b];
        int ii = pidx_g[k * 64 + b];
        if (v > mx || (v == mx && ii < ix)) { mx = v; ix = ii; }
      }
      redA[kq][b] = mx;
      redI[kq][b] = ix;
      __syncthreads();
      if (tid < 64) {
        float M = redA[0][tid];
        int ai = redI[0][tid];
#pragma unroll
        for (int w2 = 1; w2 < 4; ++w2) {
          float v = redA[w2][tid];
          int ii = redI[w2][tid];
          if (v > M || (v == M && ii < ai)) { M = v; ai = ii; }
        }
        rowp[tid] = E + (size_t)ai * kH;
        redA[0][tid] = M;
      }
      if (blockIdx.x == 0) {  // mask[t-1] (block-uniform branch)
        __syncthreads();
        float M = redA[0][b];
        float sacc = 0.f;
        for (int k = kq; k < kLB; k += 4)
          sacc += psum_g[k * 64 + b] * expf(pmax_g[k * 64 + b] - M);
        redS[kq][b] = sacc;
        __syncthreads();
        if (tid < 64) {
          float S = redS[0][tid] + redS[1][tid] + redS[2][tid] + redS[3][tid];
          mask_prev[tid] = expf(out_prev[(size_t)tid * kV + kEOS] - M) / S;
        }
      }
    }
  }
  __syncthreads();

  const int tb4 = tid & 15;
  const int tr4 = tid >> 4;
  float acc[4][4];
#pragma unroll
  for (int i = 0; i < 4; ++i)
#pragma unroll
    for (int j = 0; j < 4; ++j) acc[i][j] = 0.f;

  for (int kc = kc0; kc < kc0 + 256; kc += 64) {
#pragma unroll
    for (int l = 0; l < 4; ++l) {
      int f4 = tid + 256 * l;
      int row = f4 >> 4;
      int c4 = f4 & 15;
      float4 w = *(const float4*)(W + (size_t)(r0 + row) * kH + kc + c4 * 4);
      float wv[4] = {w.x, w.y, w.z, w.w};
#pragma unroll
      for (int cc = 0; cc < 4; ++cc) {
        int c = (cc + c4) & 3;
        Wt[(c4 * 4 + c) * 68 + row] = wv[c];
      }
    }
    if (!phase) {  // z = E[amax[b]] rows (row-major gather, coalesced 1KB/row)
#pragma unroll
      for (int l = 0; l < 4; ++l) {
        int g = tid + 256 * l;  // 0..1023
        int zb = g >> 4, k4 = g & 15;
        f32x4 v = *(const f32x4*)(rowp[zb] + kc + k4 * 4);
#pragma unroll
        for (int j = 0; j < 4; ++j) Zt[(k4 * 4 + j) * 68 + zb] = v[j];
      }
    } else {  // z = h, [k][b] layout
#pragma unroll
      for (int l = 0; l < 4; ++l) {
        int f4 = tid + 256 * l;
        int kk = f4 >> 4;
        int b4 = f4 & 15;
        *(float4*)(&Zt[kk * 68 + b4 * 4]) =
            *(const float4*)(h + (size_t)(kc + kk) * 64 + b4 * 4);
      }
    }
    __syncthreads();
#pragma unroll
    for (int kk = 0; kk < 64; ++kk) {
      float4 a = *(const float4*)(&Wt[kk * 68 + tr4 * 4]);
      float4 zb = *(const float4*)(&Zt[kk * 68 + tb4 * 4]);
      float av[4] = {a.x, a.y, a.z, a.w};
      float zv[4] = {zb.x, zb.y, zb.z, zb.w};
#pragma unroll
      for (int i = 0; i < 4; ++i)
#pragma unroll
        for (int j = 0; j < 4; ++j) acc[i][j] += av[i] * zv[j];
    }
    __syncthreads();
  }
#pragma unroll
  for (int i = 0; i < 4; ++i) {
    float4 o = make_float4(acc[i][0], acc[i][1], acc[i][2], acc[i][3]);
    *(float4*)(&part[((size_t)s * kFH + r0 + tr4 * 4 + i) * 64 + tb4 * 4]) = o;
  }
}

// ------------------------------------------------- lstm (+ hsplit fused) ----
__global__ __launch_bounds__(256) void lstm_kernel(
    const float* __restrict__ part, const float* __restrict__ bih,
    const float* __restrict__ bhh, float* __restrict__ h,
    float* __restrict__ c, unsigned short* __restrict__ Hhi,
    unsigned short* __restrict__ Hlo) {
  int g = blockIdx.x * 256 + threadIdx.x;
  int b = g & 63, u = g >> 6;
  float gate[4];
#pragma unroll
  for (int ty = 0; ty < 4; ++ty) {
    int r = ty * kH + u;
    float acc = bih[r] + bhh[r];
#pragma unroll
    for (int s2 = 0; s2 < 8; ++s2)
      acc += part[((size_t)s2 * kFH + r) * 64 + b];
    gate[ty] = acc;
  }
  float gi = 1.f / (1.f + expf(-gate[0]));
  float gf = 1.f / (1.f + expf(-gate[1]));
  float gg = tanhf(gate[2]);
  float go = 1.f / (1.f + expf(-gate[3]));
  float cn = gf * c[g] + gi * gg;
  float hn = go * tanhf(cn);
  c[g] = cn;
  h[g] = hn;
  unsigned short hb = f2bf(hn);
  Hhi[(size_t)b * kH + u] = hb;
  Hlo[(size_t)b * kH + u] = f2bf(hn - bf2f(hb));
}

// ------------------------------------------------------- logits (MFMA) ------
// out[b][v] = sum_k W[v][k] h[k][b] + bout[v], 3-term bf16 split, no LDS.
// Block 256 thr = 4 waves; wave = 32v x 64b; grid 250 (covers V exactly).
// NAMED triple-buffer prefetch (f0,f1,f2): 36 loads in flight per wave.
// k-chunk MFMA order ascending, identical to R1 -> bitwise-identical logits.
struct Frags {
  bf16x8 ah[2], al[2], bh[4], bl[4];
};

__device__ inline void load_frags(Frags& f, const unsigned short* wp0,
                                  const unsigned short* wp1,
                                  const unsigned short* lp0,
                                  const unsigned short* lp1,
                                  const unsigned short* hh,
                                  const unsigned short* hl, int ko) {
  f.ah[0] = *(const bf16x8*)(wp0 + ko);
  f.ah[1] = *(const bf16x8*)(wp1 + ko);
  f.al[0] = *(const bf16x8*)(lp0 + ko);
  f.al[1] = *(const bf16x8*)(lp1 + ko);
#pragma unroll
  for (int bt = 0; bt < 4; ++bt) {
    f.bh[bt] = *(const bf16x8*)(hh + bt * 16 * kH + ko);
    f.bl[bt] = *(const bf16x8*)(hl + bt * 16 * kH + ko);
  }
}

__device__ inline void do_mfma(const Frags& f, f32x4 acc[2][4]) {
#pragma unroll
  for (int tv = 0; tv < 2; ++tv)
#pragma unroll
    for (int bt = 0; bt < 4; ++bt) {
      acc[tv][bt] = __builtin_amdgcn_mfma_f32_16x16x32_bf16(
          f.ah[tv], f.bh[bt], acc[tv][bt], 0, 0, 0);
      acc[tv][bt] = __builtin_amdgcn_mfma_f32_16x16x32_bf16(
          f.ah[tv], f.bl[bt], acc[tv][bt], 0, 0, 0);
      acc[tv][bt] = __builtin_amdgcn_mfma_f32_16x16x32_bf16(
          f.al[tv], f.bh[bt], acc[tv][bt], 0, 0, 0);
    }
}

__global__ __launch_bounds__(256) void logits_mfma_kernel(
    const unsigned short* __restrict__ Whi, const unsigned short* __restrict__ Wlo,
    const unsigned short* __restrict__ Hhi, const unsigned short* __restrict__ Hlo,
    const float* __restrict__ bout, float* __restrict__ out,
    float* __restrict__ pmax_g, float* __restrict__ psum_g,
    int* __restrict__ pidx_g) {
  const int tid = threadIdx.x;
  const int wave = tid >> 6, lane = tid & 63;
  const int m = lane & 15, q = lane >> 4;
  const int v0 = blockIdx.x * 128 + wave * 32;
  const unsigned short* wp0 = Whi + (size_t)(v0 + m) * kH + q * 8;
  const unsigned short* wp1 = Whi + (size_t)(v0 + 16 + m) * kH + q * 8;
  const unsigned short* lp0 = Wlo + (size_t)(v0 + m) * kH + q * 8;
  const unsigned short* lp1 = Wlo + (size_t)(v0 + 16 + m) * kH + q * 8;
  const unsigned short* hh = Hhi + (size_t)m * kH + q * 8;
  const unsigned short* hl = Hlo + (size_t)m * kH + q * 8;

  f32x4 acc[2][4];
#pragma unroll
  for (int tv = 0; tv < 2; ++tv)
#pragma unroll
    for (int bt = 0; bt < 4; ++bt) acc[tv][bt] = (f32x4){0.f, 0.f, 0.f, 0.f};

  // 32 k-chunks of 32; named 3-deep rotation, 3 chunks (96 k) per iteration.
  Frags f0, f1, f2;
  load_frags(f0, wp0, wp1, lp0, lp1, hh, hl, 0);
  load_frags(f1, wp0, wp1, lp0, lp1, hh, hl, 32);
  for (int it = 0; it < 10; ++it) {
    const int base = it * 96;
    load_frags(f2, wp0, wp1, lp0, lp1, hh, hl, base + 64);
    do_mfma(f0, acc);
    load_frags(f0, wp0, wp1, lp0, lp1, hh, hl, base + 96);
    do_mfma(f1, acc);
    load_frags(f1, wp0, wp1, lp0, lp1, hh, hl, base + 128);
    do_mfma(f2, acc);
  }
  do_mfma(f0, acc);  // k = 960
  do_mfma(f1, acc);  // k = 992

  // bias in-place; store logits. D layout: row(v)=q*4+reg, col(b)=lane&15.
  float4 bo0 = *(const float4*)(bout + v0 + q * 4);
  float4 bo1 = *(const float4*)(bout + v0 + 16 + q * 4);
#pragma unroll
  for (int tv = 0; tv < 2; ++tv) {
    float4 bo = tv ? bo1 : bo0;
#pragma unroll
    for (int bt = 0; bt < 4; ++bt) {
      int b = bt * 16 + m;
      f32x4 a = acc[tv][bt];
      a[0] += bo.x; a[1] += bo.y; a[2] += bo.z; a[3] += bo.w;
      acc[tv][bt] = a;
      float4 o = make_float4(a[0], a[1], a[2], a[3]);
      *(float4*)(out + (size_t)b * kV + v0 + tv * 16 + q * 4) = o;
    }
  }

  // ---- per-block softmax/argmax partials, layout [blk][64] (coalesced)
  __shared__ float lred[4][4][64];
  __shared__ int lidx[4][4][64];
  __shared__ float bbm[64];
  const int blk = blockIdx.x;
  const int vbase = blk * 128;

#pragma unroll
  for (int bt = 0; bt < 4; ++bt) {
    float pmv = -INFINITY;
    int piv = 0x7fffffff;
#pragma unroll
    for (int tv = 0; tv < 2; ++tv)
#pragma unroll
      for (int r = 0; r < 4; ++r) {
        float val = acc[tv][bt][r];
        int v = vbase + wave * 32 + tv * 16 + q * 4 + r;
        if (val > pmv) { pmv = val; piv = v; }  // strict >, v ascending
      }
    lred[wave][q][bt * 16 + m] = pmv;
    lidx[wave][q][bt * 16 + m] = piv;
  }
  __syncthreads();
  if (tid < 64) {
    float bm = -INFINITY;
    int bi = 0x7fffffff;
#pragma unroll
    for (int w = 0; w < 4; ++w)
#pragma unroll
      for (int qq = 0; qq < 4; ++qq) {
        float v2 = lred[w][qq][tid];
        int i2 = lidx[w][qq][tid];
        if (v2 > bm || (v2 == bm && i2 < bi)) { bm = v2; bi = i2; }
      }
    bbm[tid] = bm;
    pmax_g[(size_t)blk * 64 + tid] = bm;
    pidx_g[(size_t)blk * 64 + tid] = bi;
  }
  __syncthreads();
#pragma unroll
  for (int bt = 0; bt < 4; ++bt) {
    float bm = bbm[bt * 16 + m];
    float s = 0.f;
#pragma unroll
    for (int tv = 0; tv < 2; ++tv)
#pragma unroll
      for (int r = 0; r < 4; ++r) s += expf(acc[tv][bt][r] - bm);
    lred[wave][q][bt * 16 + m] = s;
  }
  __syncthreads();
  if (tid < 64) {
    float s = 0.f;
#pragma unroll
    for (int w = 0; w < 4; ++w)
#pragma unroll
      for (int qq = 0; qq < 4; ++qq) s += lred[w][qq][tid];
    psum_g[(size_t)blk * 64 + tid] = s;
  }
}

// --------------------------------------------- final mask (t = T-1 only) ----
__global__ __launch_bounds__(256) void final_mask_kernel(
    const float* __restrict__ pm, const float* __restrict__ ps,
    const float* __restrict__ out_t, float* __restrict__ mask) {
  __shared__ float rm[4][64];
  __shared__ float rs[4][64];
  const int tid = threadIdx.x;
  const int b = tid & 63, kq = tid >> 6;
  float mx = -INFINITY;
  for (int k = kq; k < kLB; k += 4) {
    float v = pm[k * 64 + b];
    if (v > mx) mx = v;
  }
  rm[kq][b] = mx;
  __syncthreads();
  if (tid < 64) {
    float M = fmaxf(fmaxf(rm[0][tid], rm[1][tid]), fmaxf(rm[2][tid], rm[3][tid]));
    rm[0][tid] = M;
  }
  __syncthreads();
  float M = rm[0][b];
  float s = 0.f;
  for (int k = kq; k < kLB; k += 4)
    s += ps[k * 64 + b] * expf(pm[k * 64 + b] - M);
  rs[kq][b] = s;
  __syncthreads();
  if (tid < 64) {
    float S = rs[0][tid] + rs[1][tid] + rs[2][tid] + rs[3][tid];
    mask[tid] = expf(out_t[(size_t)tid * kV + kEOS] - M) / S;
  }
}

// -------------------------------------------------------------- launch ------
extern "C" void kernel_launch(void* const* d_in, const int* in_sizes, int n_in,
                              void* d_out, int out_size, void* d_ws,
                              size_t ws_size, hipStream_t stream) {
  const float* E = (const float*)d_in[0];
  const float* Wih = (const float*)d_in[1];
  const float* Whh = (const float*)d_in[2];
  const float* bih = (const float*)d_in[3];
  const float* bhh = (const float*)d_in[4];
  const float* Wout = (const float*)d_in[5];
  const float* bout = (const float*)d_in[6];
  const float* eh = (const float*)d_in[7];
  const float* ec = (const float*)d_in[8];
  float* out = (float*)d_out;
  float* ws = (float*)d_ws;

  float* h = ws + 65536;
  float* c = ws + 131072;
  float* part = ws + 196608;  // 8*4096*64 floats, ends 2293760
  float* pmaxg = ws + 2293760;
  float* psumg = ws + 2310144;
  int* pidxg = (int*)(ws + 2326528);
  unsigned short* Whi = (unsigned short*)(ws + 2359296);
  unsigned short* Wlo = Whi + (size_t)kV * kH;
  unsigned short* Hhi = Wlo + (size_t)kV * kH;
  unsigned short* Hlo = Hhi + (size_t)kB * kH;
  float* maskbase = out + (size_t)kT * kB * kV;

  init_kernel<<<512, 256, 0, stream>>>(eh, ec, ws);
  wsplit_kernel<<<kV, 256, 0, stream>>>(Wout, Whi, Wlo);
  for (int t = 0; t < kT; ++t) {
    float* out_t = out + (size_t)t * kB * kV;
    const float* out_prev = t ? out + (size_t)(t - 1) * kB * kV : nullptr;
    float* mask_prev = t ? maskbase + (size_t)(t - 1) * kB : nullptr;
    gates_kernel<<<dim3(64, 8), 256, 0, stream>>>(
        Wih, Whh, E, h, part, pmaxg, psumg, pidxg, out_prev, mask_prev, t);
    lstm_kernel<<<256, 256, 0, stream>>>(part, bih, bhh, h, c, Hhi, Hlo);
    logits_mfma_kernel<<<kLB, 256, 0, stream>>>(Whi, Wlo, Hhi, Hlo, bout,
                                                out_t, pmaxg, psumg, pidxg);
  }
  final_mask_kernel<<<1, 256, 0, stream>>>(
      pmaxg, psumg, out + (size_t)(kT - 1) * kB * kV,
      maskbase + (size_t)(kT - 1) * kB);
}

// Round 7
// 3000.533 us; speedup vs baseline: 1.8881x; 1.2576x over previous
//
#include <hip/hip_runtime.h>
#include <math.h>

// DecoderLSTM greedy decode, MI355X. V=32000 H=1024 T=32 B=64.
// Logits GEMM: bf16 MFMA (16x16x32) with 3-term split (hi*hi + hi*lo + lo*hi),
// fp32 accumulate -> per-logit error ~1e-5, no feedback into recurrence.
// Gates GEMM stays fp32 (recurrence amplifies its error ~10^3x over 32 steps).
//
// R7 = EXACT R1 kernel set (2972us verified: init/wsplit/gates/lstm+hsplit/
// logits/finalize, 4 dispatches/step) + ONE change: logits K-split x2.
//   512-thr blocks, 8 waves: waves 0-3 k=[0,512), waves 4-7 k=[512,1024),
//   same f0/f1 double-buffered loop per half; padded-LDS combine
//   (combf[4][32][65], conflict-free); epilogue on waves 0-3, barriers
//   block-wide. Doubles waves/SIMD 1->2 => ~2x memory-level parallelism on
//   the 131 MB/step W stream (R1 logits ran ~2 TB/s, latency-bound).
//
// ws layout (R1):
//   floats: x[1024][64]@0  h[1024][64]@65536  c[1024][64]@131072
//           part[8][4096][64]@196608  (ends 2293760)
//           pmax[64][256]@2293760 psum[64][256]@2310144 pidx(int)[64][256]@2326528
//   ushort (bf16), at float offset 2359296:
//           Whi[32000][1024], Wlo[32000][1024], Hhi[64][1024], Hlo[64][1024]

typedef short bf16x8 __attribute__((ext_vector_type(8)));
typedef float f32x4 __attribute__((ext_vector_type(4)));

constexpr int kH = 1024;
constexpr int kFH = 4096;
constexpr int kB = 64;
constexpr int kV = 32000;
constexpr int kT = 32;
constexpr int kSOS = 1;
constexpr int kEOS = 2;

__device__ inline unsigned short f2bf(float f) {  // RNE float->bf16
  unsigned int u = __float_as_uint(f);
  u += 0x7fffu + ((u >> 16) & 1u);
  return (unsigned short)(u >> 16);
}
__device__ inline float bf2f(unsigned short h) {
  return __uint_as_float(((unsigned int)h) << 16);
}

// ---------------------------------------------------------------- init ------
__global__ __launch_bounds__(256) void init_kernel(
    const float* __restrict__ E, const float* __restrict__ eh,
    const float* __restrict__ ec, float* __restrict__ ws) {
  int g = blockIdx.x * 256 + threadIdx.x;  // 0..65535
  int u = g >> 6, b = g & 63;
  float* x = ws;
  float* h = ws + 65536;
  float* c = ws + 131072;
  x[g] = E[(size_t)kSOS * kH + u];
  h[u * 64 + b] = eh[(size_t)b * kH + u];
  c[u * 64 + b] = ec[(size_t)b * kH + u];
}

// ------------------------------------------------------------- W split ------
// Whi = bf16(W), Wlo = bf16(W - Whi). 32000*1024 elems, 4/thread.
__global__ __launch_bounds__(256) void wsplit_kernel(
    const float* __restrict__ W, unsigned short* __restrict__ hi,
    unsigned short* __restrict__ lo) {
  size_t i = ((size_t)blockIdx.x * 256 + threadIdx.x) * 4;
  float4 w = *(const float4*)(W + i);
  unsigned short h0 = f2bf(w.x), h1 = f2bf(w.y), h2 = f2bf(w.z), h3 = f2bf(w.w);
  ushort4 hv = make_ushort4(h0, h1, h2, h3);
  ushort4 lv = make_ushort4(f2bf(w.x - bf2f(h0)), f2bf(w.y - bf2f(h1)),
                            f2bf(w.z - bf2f(h2)), f2bf(w.w - bf2f(h3)));
  *(ushort4*)(hi + i) = hv;
  *(ushort4*)(lo + i) = lv;
}

// --------------------------------------------------------------- gates ------
// part[s][r][b] += W[r][k] * z[k][b]. grid(64,8). fp32 (R1-verified).
__global__ __launch_bounds__(256) void gates_kernel(
    const float* __restrict__ Wih, const float* __restrict__ Whh,
    const float* __restrict__ x, const float* __restrict__ h,
    float* __restrict__ part) {
  __shared__ __align__(16) float Wt[64 * 68];
  __shared__ __align__(16) float Zt[64 * 68];
  const int tid = threadIdx.x;
  const int s = blockIdx.y;
  const int r0 = blockIdx.x * 64;
  const int phase = s >> 2;
  const int kc0 = (s & 3) * 256;
  const float* __restrict__ W = phase ? Whh : Wih;
  const float* __restrict__ z = phase ? h : x;
  const int tb4 = tid & 15;
  const int tr4 = tid >> 4;
  float acc[4][4];
#pragma unroll
  for (int i = 0; i < 4; ++i)
#pragma unroll
    for (int j = 0; j < 4; ++j) acc[i][j] = 0.f;

  for (int kc = kc0; kc < kc0 + 256; kc += 64) {
#pragma unroll
    for (int l = 0; l < 4; ++l) {
      int f4 = tid + 256 * l;
      int row = f4 >> 4;
      int c4 = f4 & 15;
      float4 w = *(const float4*)(W + (size_t)(r0 + row) * kH + kc + c4 * 4);
      float wv[4] = {w.x, w.y, w.z, w.w};
#pragma unroll
      for (int cc = 0; cc < 4; ++cc) {
        int c = (cc + c4) & 3;
        Wt[(c4 * 4 + c) * 68 + row] = wv[c];
      }
    }
#pragma unroll
    for (int l = 0; l < 4; ++l) {
      int f4 = tid + 256 * l;
      int kk = f4 >> 4;
      int b4 = f4 & 15;
      *(float4*)(&Zt[kk * 68 + b4 * 4]) =
          *(const float4*)(z + (size_t)(kc + kk) * 64 + b4 * 4);
    }
    __syncthreads();
#pragma unroll
    for (int kk = 0; kk < 64; ++kk) {
      float4 a = *(const float4*)(&Wt[kk * 68 + tr4 * 4]);
      float4 zb = *(const float4*)(&Zt[kk * 68 + tb4 * 4]);
      float av[4] = {a.x, a.y, a.z, a.w};
      float zv[4] = {zb.x, zb.y, zb.z, zb.w};
#pragma unroll
      for (int i = 0; i < 4; ++i)
#pragma unroll
        for (int j = 0; j < 4; ++j) acc[i][j] += av[i] * zv[j];
    }
    __syncthreads();
  }
#pragma unroll
  for (int i = 0; i < 4; ++i) {
    float4 o = make_float4(acc[i][0], acc[i][1], acc[i][2], acc[i][3]);
    *(float4*)(&part[((size_t)s * kFH + r0 + tr4 * 4 + i) * 64 + tb4 * 4]) = o;
  }
}

// ------------------------------------------------- lstm (+ hsplit fused) ----
__global__ __launch_bounds__(256) void lstm_kernel(
    const float* __restrict__ part, const float* __restrict__ bih,
    const float* __restrict__ bhh, float* __restrict__ h,
    float* __restrict__ c, unsigned short* __restrict__ Hhi,
    unsigned short* __restrict__ Hlo) {
  int g = blockIdx.x * 256 + threadIdx.x;
  int b = g & 63, u = g >> 6;
  float gate[4];
#pragma unroll
  for (int ty = 0; ty < 4; ++ty) {
    int r = ty * kH + u;
    float acc = bih[r] + bhh[r];
#pragma unroll
    for (int s2 = 0; s2 < 8; ++s2)
      acc += part[((size_t)s2 * kFH + r) * 64 + b];
    gate[ty] = acc;
  }
  float gi = 1.f / (1.f + expf(-gate[0]));
  float gf = 1.f / (1.f + expf(-gate[1]));
  float gg = tanhf(gate[2]);
  float go = 1.f / (1.f + expf(-gate[3]));
  float cn = gf * c[g] + gi * gg;
  float hn = go * tanhf(cn);
  c[g] = cn;
  h[g] = hn;
  unsigned short hb = f2bf(hn);
  Hhi[(size_t)b * kH + u] = hb;
  Hlo[(size_t)b * kH + u] = f2bf(hn - bf2f(hb));
}

// ------------------------------------------------------- logits (MFMA) ------
// out[b][v] = sum_k W[v][k] h[k][b] + bout[v], 3-term bf16 split, no LDS in
// main loop. 512 thr = 8 waves: wave = (kh = wave>>2, ws = wave&3);
// v0 = blk*128 + ws*32, k-range = [kh*512, kh*512+512). Same R1 f0/f1
// double-buffer per half; LDS combine; epilogue on kh==0 waves.
struct Frags {
  bf16x8 ah[2], al[2], bh[4], bl[4];
};

__device__ inline void load_frags(Frags& f, const unsigned short* wp0,
                                  const unsigned short* wp1,
                                  const unsigned short* lp0,
                                  const unsigned short* lp1,
                                  const unsigned short* hh,
                                  const unsigned short* hl, int ko) {
  f.ah[0] = *(const bf16x8*)(wp0 + ko);
  f.ah[1] = *(const bf16x8*)(wp1 + ko);
  f.al[0] = *(const bf16x8*)(lp0 + ko);
  f.al[1] = *(const bf16x8*)(lp1 + ko);
#pragma unroll
  for (int bt = 0; bt < 4; ++bt) {
    f.bh[bt] = *(const bf16x8*)(hh + bt * 16 * kH + ko);
    f.bl[bt] = *(const bf16x8*)(hl + bt * 16 * kH + ko);
  }
}

__device__ inline void do_mfma(const Frags& f, f32x4 acc[2][4]) {
#pragma unroll
  for (int tv = 0; tv < 2; ++tv)
#pragma unroll
    for (int bt = 0; bt < 4; ++bt) {
      acc[tv][bt] = __builtin_amdgcn_mfma_f32_16x16x32_bf16(
          f.ah[tv], f.bh[bt], acc[tv][bt], 0, 0, 0);
      acc[tv][bt] = __builtin_amdgcn_mfma_f32_16x16x32_bf16(
          f.ah[tv], f.bl[bt], acc[tv][bt], 0, 0, 0);
      acc[tv][bt] = __builtin_amdgcn_mfma_f32_16x16x32_bf16(
          f.al[tv], f.bh[bt], acc[tv][bt], 0, 0, 0);
    }
}

__global__ __launch_bounds__(512, 2) void logits_mfma_kernel(
    const unsigned short* __restrict__ Whi, const unsigned short* __restrict__ Wlo,
    const unsigned short* __restrict__ Hhi, const unsigned short* __restrict__ Hlo,
    const float* __restrict__ bout, float* __restrict__ out,
    float* __restrict__ pmax_g, float* __restrict__ psum_g,
    int* __restrict__ pidx_g) {
  const int tid = threadIdx.x;
  const int wave = tid >> 6, lane = tid & 63;
  const int ws = wave & 3;   // v-subtile within block
  const int kh = wave >> 2;  // k-half
  const int m = lane & 15, q = lane >> 4;
  const int v0 = blockIdx.x * 128 + ws * 32;
  const int koff = kh * 512;
  const unsigned short* wp0 = Whi + (size_t)(v0 + m) * kH + koff + q * 8;
  const unsigned short* wp1 = Whi + (size_t)(v0 + 16 + m) * kH + koff + q * 8;
  const unsigned short* lp0 = Wlo + (size_t)(v0 + m) * kH + koff + q * 8;
  const unsigned short* lp1 = Wlo + (size_t)(v0 + 16 + m) * kH + koff + q * 8;
  const unsigned short* hh = Hhi + (size_t)m * kH + koff + q * 8;
  const unsigned short* hl = Hlo + (size_t)m * kH + koff + q * 8;

  f32x4 acc[2][4];
#pragma unroll
  for (int tv = 0; tv < 2; ++tv)
#pragma unroll
    for (int bt = 0; bt < 4; ++bt) acc[tv][bt] = (f32x4){0.f, 0.f, 0.f, 0.f};

  Frags f0, f1;
  load_frags(f0, wp0, wp1, lp0, lp1, hh, hl, 0);
  // 16 k-chunks of 32 per half, R1's exact double-buffer pattern
  for (int kc = 0; kc < 512; kc += 64) {
    if (kc + 32 < 512) load_frags(f1, wp0, wp1, lp0, lp1, hh, hl, kc + 32);
    do_mfma(f0, acc);
    if (kc + 64 < 512) load_frags(f0, wp0, wp1, lp0, lp1, hh, hl, kc + 64);
    do_mfma(f1, acc);
  }

  // ---- combine the two K-halves (padded LDS, lane-contiguous: no conflicts)
  __shared__ float combf[4][32][65];  // 33.3 KB
  if (kh == 1) {
#pragma unroll
    for (int tv = 0; tv < 2; ++tv)
#pragma unroll
      for (int bt = 0; bt < 4; ++bt)
#pragma unroll
        for (int r = 0; r < 4; ++r)
          combf[ws][(tv * 4 + bt) * 4 + r][lane] = acc[tv][bt][r];
  }
  __syncthreads();
  if (kh == 0) {
#pragma unroll
    for (int tv = 0; tv < 2; ++tv)
#pragma unroll
      for (int bt = 0; bt < 4; ++bt)
#pragma unroll
        for (int r = 0; r < 4; ++r)
          acc[tv][bt][r] += combf[ws][(tv * 4 + bt) * 4 + r][lane];
  }

  // bias + store logits (kh==0 waves). D layout: row(v)=q*4+reg, col=lane&15.
  if (kh == 0) {
    float4 bo0 = *(const float4*)(bout + v0 + q * 4);
    float4 bo1 = *(const float4*)(bout + v0 + 16 + q * 4);
#pragma unroll
    for (int tv = 0; tv < 2; ++tv) {
      float4 bo = tv ? bo1 : bo0;
#pragma unroll
      for (int bt = 0; bt < 4; ++bt) {
        int b = bt * 16 + m;
        f32x4 a = acc[tv][bt];
        a[0] += bo.x; a[1] += bo.y; a[2] += bo.z; a[3] += bo.w;
        acc[tv][bt] = a;
        float4 o = make_float4(a[0], a[1], a[2], a[3]);
        *(float4*)(out + (size_t)b * kV + v0 + tv * 16 + q * 4) = o;
      }
    }
  }

  // ---- per-block softmax/argmax partials (R1 layout [b][256]); barriers are
  // block-wide (all 512 threads), work guarded to kh==0.
  __shared__ float lred[4][4][64];
  __shared__ int lidx[4][4][64];
  __shared__ float bbm[64];
  const int blk = blockIdx.x;
  const int vbase = blk * 128;

  if (kh == 0) {
#pragma unroll
    for (int bt = 0; bt < 4; ++bt) {
      float pmv = -INFINITY;
      int piv = 0x7fffffff;
#pragma unroll
      for (int tv = 0; tv < 2; ++tv)
#pragma unroll
        for (int r = 0; r < 4; ++r) {
          float val = acc[tv][bt][r];
          int v = vbase + ws * 32 + tv * 16 + q * 4 + r;
          if (val > pmv) { pmv = val; piv = v; }  // strict >, v ascending
        }
      lred[ws][q][bt * 16 + m] = pmv;
      lidx[ws][q][bt * 16 + m] = piv;
    }
  }
  __syncthreads();
  if (tid < 64) {
    float bm = -INFINITY;
    int bi = 0x7fffffff;
#pragma unroll
    for (int w = 0; w < 4; ++w)
#pragma unroll
      for (int qq = 0; qq < 4; ++qq) {
        float v2 = lred[w][qq][tid];
        int i2 = lidx[w][qq][tid];
        if (v2 > bm || (v2 == bm && i2 < bi)) { bm = v2; bi = i2; }
      }
    bbm[tid] = bm;
    pmax_g[(size_t)tid * 256 + blk] = bm;
    pidx_g[(size_t)tid * 256 + blk] = bi;
  }
  __syncthreads();
  if (kh == 0) {
#pragma unroll
    for (int bt = 0; bt < 4; ++bt) {
      float bm = bbm[bt * 16 + m];
      float s = 0.f;
#pragma unroll
      for (int tv = 0; tv < 2; ++tv)
#pragma unroll
        for (int r = 0; r < 4; ++r) s += expf(acc[tv][bt][r] - bm);
      lred[ws][q][bt * 16 + m] = s;
    }
  }
  __syncthreads();
  if (tid < 64) {
    float s = 0.f;
#pragma unroll
    for (int w = 0; w < 4; ++w)
#pragma unroll
      for (int qq = 0; qq < 4; ++qq) s += lred[w][qq][tid];
    psum_g[(size_t)tid * 256 + blk] = s;
  }
}

// ----------------------------------------------- finalize: reduce partials --
// grid 64 (one block per b): global max/argmax/sum from 250 partials, mask,
// and x_next = E[argmax] gather. (R1-verified.)
__global__ __launch_bounds__(256) void finalize_kernel(
    const float* __restrict__ pm, const float* __restrict__ ps,
    const int* __restrict__ pig, const float* __restrict__ out_t,
    const float* __restrict__ E, float* __restrict__ x,
    float* __restrict__ mask) {
  __shared__ float sm[256];
  __shared__ int si[256];
  __shared__ float ss[256];
  const int b = blockIdx.x, tid = threadIdx.x;
  float m = -INFINITY;
  int idx = 0x7fffffff;
  if (tid < 250) {
    m = pm[(size_t)b * 256 + tid];
    idx = pig[(size_t)b * 256 + tid];
  }
  sm[tid] = m;
  si[tid] = idx;
  __syncthreads();
  for (int off = 128; off > 0; off >>= 1) {
    if (tid < off) {
      float o = sm[tid + off];
      int oi = si[tid + off];
      if (o > sm[tid] || (o == sm[tid] && oi < si[tid])) {
        sm[tid] = o;
        si[tid] = oi;
      }
    }
    __syncthreads();
  }
  const float M = sm[0];
  const int amax = si[0];
  float term = 0.f;
  if (tid < 250) term = ps[(size_t)b * 256 + tid] * expf(m - M);
  ss[tid] = term;
  __syncthreads();
  for (int off = 128; off > 0; off >>= 1) {
    if (tid < off) ss[tid] += ss[tid + off];
    __syncthreads();
  }
  if (tid == 0) mask[b] = expf(out_t[(size_t)b * kV + kEOS] - M) / ss[0];
  for (int u = tid; u < kH; u += 256)
    x[u * 64 + b] = E[(size_t)amax * kH + u];
}

// -------------------------------------------------------------- launch ------
extern "C" void kernel_launch(void* const* d_in, const int* in_sizes, int n_in,
                              void* d_out, int out_size, void* d_ws,
                              size_t ws_size, hipStream_t stream) {
  const float* E = (const float*)d_in[0];
  const float* Wih = (const float*)d_in[1];
  const float* Whh = (const float*)d_in[2];
  const float* bih = (const float*)d_in[3];
  const float* bhh = (const float*)d_in[4];
  const float* Wout = (const float*)d_in[5];
  const float* bout = (const float*)d_in[6];
  const float* eh = (const float*)d_in[7];
  const float* ec = (const float*)d_in[8];
  float* out = (float*)d_out;
  float* ws = (float*)d_ws;

  float* x = ws;
  float* h = ws + 65536;
  float* c = ws + 131072;
  float* part = ws + 196608;
  float* pmaxg = ws + 2293760;
  float* psumg = ws + 2310144;
  int* pidxg = (int*)(ws + 2326528);
  unsigned short* Whi = (unsigned short*)(ws + 2359296);
  unsigned short* Wlo = Whi + (size_t)kV * kH;
  unsigned short* Hhi = Wlo + (size_t)kV * kH;
  unsigned short* Hlo = Hhi + (size_t)kB * kH;

  init_kernel<<<256, 256, 0, stream>>>(E, eh, ec, ws);
  wsplit_kernel<<<kV, 256, 0, stream>>>(Wout, Whi, Wlo);
  for (int t = 0; t < kT; ++t) {
    float* out_t = out + (size_t)t * kB * kV;
    gates_kernel<<<dim3(64, 8), 256, 0, stream>>>(Wih, Whh, x, h, part);
    lstm_kernel<<<256, 256, 0, stream>>>(part, bih, bhh, h, c, Hhi, Hlo);
    logits_mfma_kernel<<<250, 512, 0, stream>>>(
        Whi, Wlo, Hhi, Hlo, bout, out_t, pmaxg, psumg, pidxg);
    finalize_kernel<<<64, 256, 0, stream>>>(pmaxg, psumg, pidxg, out_t, E, x,
                                            out + (size_t)kT * kB * kV + t * kB);
  }
}

// Round 9
// 2758.940 us; speedup vs baseline: 2.0534x; 1.0876x over previous
//
#include <hip/hip_runtime.h>
#include <math.h>

// DecoderLSTM greedy decode, MI355X. V=32000 H=1024 T=32 B=64.
// Logits GEMM: bf16 MFMA (16x16x32) with 3-term split (hi*hi + hi*lo + lo*hi),
// fp32 accumulate -> per-logit error ~1e-5, no feedback into recurrence.
// Gates GEMM stays fp32 (recurrence amplifies its error ~10^3x over 32 steps).
//
// R9 == R8 resubmit (container failed twice; same infra signature as R2->R3.
// Kernel audited: no spins/fences, all accesses bounds- and 16B-align-checked,
// pack<->read address map verified element-wise, ws footprint unchanged).
// R8 = R7 (3000us; R1-equal) + ONE change: W packed in consumption order.
//   Old logits W reads: 64 scattered 16B segments per frag-load (lanes read
//   16 rows strided 1KB) -> 16x minimal L2 transactions, ~2-3 TB/s effective.
//   New: wsplit_pack writes Wpk[blk][wave][kcl][frag][lane][8ush]; each wave
//   streams a contiguous 64KB panel, 1KB fully-coalesced per load. Logits
//   kernel structure/MFMA order unchanged -> bitwise-identical logits
//   (absmax canary 0.0078125).
//
// ws layout (R1/R7):
//   floats: x[1024][64]@0  h[1024][64]@65536  c[1024][64]@131072
//           part[8][4096][64]@196608  (ends 2293760)
//           pmax[64][256]@2293760 psum[64][256]@2310144 pidx(int)[64][256]@2326528
//   ushort at float offset 2359296: Wpk[250*8*32768], Hhi[64][1024], Hlo[64][1024]

typedef short bf16x8 __attribute__((ext_vector_type(8)));
typedef unsigned short ush8 __attribute__((ext_vector_type(8)));
typedef float f32x4 __attribute__((ext_vector_type(4)));

constexpr int kH = 1024;
constexpr int kFH = 4096;
constexpr int kB = 64;
constexpr int kV = 32000;
constexpr int kT = 32;
constexpr int kSOS = 1;
constexpr int kEOS = 2;

__device__ inline unsigned short f2bf(float f) {  // RNE float->bf16
  unsigned int u = __float_as_uint(f);
  u += 0x7fffu + ((u >> 16) & 1u);
  return (unsigned short)(u >> 16);
}
__device__ inline float bf2f(unsigned short h) {
  return __uint_as_float(((unsigned int)h) << 16);
}

// ---------------------------------------------------------------- init ------
__global__ __launch_bounds__(256) void init_kernel(
    const float* __restrict__ E, const float* __restrict__ eh,
    const float* __restrict__ ec, float* __restrict__ ws) {
  int g = blockIdx.x * 256 + threadIdx.x;  // 0..65535
  int u = g >> 6, b = g & 63;
  float* x = ws;
  float* h = ws + 65536;
  float* c = ws + 131072;
  x[g] = E[(size_t)kSOS * kH + u];
  h[u * 64 + b] = eh[(size_t)b * kH + u];
  c[u * 64 + b] = ec[(size_t)b * kH + u];
}

// -------------------------------------------------- W split + pack ----------
// One block per (blk, wave) panel: v rows [v0, v0+32), k in [k0, k0+512).
// Two passes (hi, lo) through a padded LDS tile; reads coalesced float4,
// writes coalesced 16B in exact logits consumption order:
//   Wpk[(blk*8+wave)*32768 + kcl*2048 + frag*512 + lane*8 + e]
//   frag: 0=hi rows m, 1=hi rows 16+m, 2=lo rows m, 3=lo rows 16+m
//   v = v0 + (frag&1)*16 + (lane&15), k = k0 + kcl*32 + (lane>>4)*8 + e
__global__ __launch_bounds__(256) void wsplit_pack_kernel(
    const float* __restrict__ W, unsigned short* __restrict__ Wpk) {
  __shared__ __align__(16) unsigned short Tl[32][520];  // 33.3 KB, padded
  const int tid = threadIdx.x;
  const int blk = blockIdx.x >> 3;
  const int wave = blockIdx.x & 7;
  const int ws = wave & 3, kh = wave >> 2;
  const int v0 = blk * 128 + ws * 32;
  const int k0 = kh * 512;
  unsigned short* dst = Wpk + (size_t)blockIdx.x * 32768;

  for (int pass = 0; pass < 2; ++pass) {
    // load 32 rows x 512 k of W, split, stage hi (pass 0) or lo (pass 1)
#pragma unroll
    for (int l = 0; l < 16; ++l) {
      int idx = tid + 256 * l;  // 0..4095 float4-slots
      int row = idx >> 7, c4 = idx & 127;
      float4 w = *(const float4*)(W + (size_t)(v0 + row) * kH + k0 + c4 * 4);
      unsigned short h0 = f2bf(w.x), h1 = f2bf(w.y), h2 = f2bf(w.z),
                     h3 = f2bf(w.w);
      ushort4 v;
      if (pass == 0) {
        v = make_ushort4(h0, h1, h2, h3);
      } else {
        v = make_ushort4(f2bf(w.x - bf2f(h0)), f2bf(w.y - bf2f(h1)),
                         f2bf(w.z - bf2f(h2)), f2bf(w.w - bf2f(h3)));
      }
      *(ushort4*)&Tl[row][c4 * 4] = v;
    }
    __syncthreads();
    // write this pass's 2048 ush8 frags (frag = pass*2 + fr_local)
#pragma unroll
    for (int l = 0; l < 8; ++l) {
      int o8 = tid + 256 * l;  // 0..2047
      int kcl = o8 >> 7;
      int rem = o8 & 127;
      int frl = rem >> 6;      // 0/1 -> rows m / 16+m
      int lane = rem & 63;
      int m = lane & 15, q = lane >> 4;
      int row = frl * 16 + m;
      int col = kcl * 32 + q * 8;
      size_t didx = (size_t)(kcl * 4 + pass * 2 + frl) * 64 + lane;
      *(ush8*)(dst + didx * 8) = *(const ush8*)&Tl[row][col];
    }
    __syncthreads();
  }
}

// --------------------------------------------------------------- gates ------
// part[s][r][b] += W[r][k] * z[k][b]. grid(64,8). fp32 (R1-verified).
__global__ __launch_bounds__(256) void gates_kernel(
    const float* __restrict__ Wih, const float* __restrict__ Whh,
    const float* __restrict__ x, const float* __restrict__ h,
    float* __restrict__ part) {
  __shared__ __align__(16) float Wt[64 * 68];
  __shared__ __align__(16) float Zt[64 * 68];
  const int tid = threadIdx.x;
  const int s = blockIdx.y;
  const int r0 = blockIdx.x * 64;
  const int phase = s >> 2;
  const int kc0 = (s & 3) * 256;
  const float* __restrict__ W = phase ? Whh : Wih;
  const float* __restrict__ z = phase ? h : x;
  const int tb4 = tid & 15;
  const int tr4 = tid >> 4;
  float acc[4][4];
#pragma unroll
  for (int i = 0; i < 4; ++i)
#pragma unroll
    for (int j = 0; j < 4; ++j) acc[i][j] = 0.f;

  for (int kc = kc0; kc < kc0 + 256; kc += 64) {
#pragma unroll
    for (int l = 0; l < 4; ++l) {
      int f4 = tid + 256 * l;
      int row = f4 >> 4;
      int c4 = f4 & 15;
      float4 w = *(const float4*)(W + (size_t)(r0 + row) * kH + kc + c4 * 4);
      float wv[4] = {w.x, w.y, w.z, w.w};
#pragma unroll
      for (int cc = 0; cc < 4; ++cc) {
        int c = (cc + c4) & 3;
        Wt[(c4 * 4 + c) * 68 + row] = wv[c];
      }
    }
#pragma unroll
    for (int l = 0; l < 4; ++l) {
      int f4 = tid + 256 * l;
      int kk = f4 >> 4;
      int b4 = f4 & 15;
      *(float4*)(&Zt[kk * 68 + b4 * 4]) =
          *(const float4*)(z + (size_t)(kc + kk) * 64 + b4 * 4);
    }
    __syncthreads();
#pragma unroll
    for (int kk = 0; kk < 64; ++kk) {
      float4 a = *(const float4*)(&Wt[kk * 68 + tr4 * 4]);
      float4 zb = *(const float4*)(&Zt[kk * 68 + tb4 * 4]);
      float av[4] = {a.x, a.y, a.z, a.w};
      float zv[4] = {zb.x, zb.y, zb.z, zb.w};
#pragma unroll
      for (int i = 0; i < 4; ++i)
#pragma unroll
        for (int j = 0; j < 4; ++j) acc[i][j] += av[i] * zv[j];
    }
    __syncthreads();
  }
#pragma unroll
  for (int i = 0; i < 4; ++i) {
    float4 o = make_float4(acc[i][0], acc[i][1], acc[i][2], acc[i][3]);
    *(float4*)(&part[((size_t)s * kFH + r0 + tr4 * 4 + i) * 64 + tb4 * 4]) = o;
  }
}

// ------------------------------------------------- lstm (+ hsplit fused) ----
__global__ __launch_bounds__(256) void lstm_kernel(
    const float* __restrict__ part, const float* __restrict__ bih,
    const float* __restrict__ bhh, float* __restrict__ h,
    float* __restrict__ c, unsigned short* __restrict__ Hhi,
    unsigned short* __restrict__ Hlo) {
  int g = blockIdx.x * 256 + threadIdx.x;
  int b = g & 63, u = g >> 6;
  float gate[4];
#pragma unroll
  for (int ty = 0; ty < 4; ++ty) {
    int r = ty * kH + u;
    float acc = bih[r] + bhh[r];
#pragma unroll
    for (int s2 = 0; s2 < 8; ++s2)
      acc += part[((size_t)s2 * kFH + r) * 64 + b];
    gate[ty] = acc;
  }
  float gi = 1.f / (1.f + expf(-gate[0]));
  float gf = 1.f / (1.f + expf(-gate[1]));
  float gg = tanhf(gate[2]);
  float go = 1.f / (1.f + expf(-gate[3]));
  float cn = gf * c[g] + gi * gg;
  float hn = go * tanhf(cn);
  c[g] = cn;
  h[g] = hn;
  unsigned short hb = f2bf(hn);
  Hhi[(size_t)b * kH + u] = hb;
  Hlo[(size_t)b * kH + u] = f2bf(hn - bf2f(hb));
}

// ------------------------------------------------------- logits (MFMA) ------
// out[b][v] = sum_k W[v][k] h[k][b] + bout[v]. 512 thr = 8 waves:
// wave = (kh = wave>>2, ws = wave&3); v0 = blk*128 + ws*32,
// k-range [kh*512, +512). W from packed consumption-order panels (1KB
// coalesced per frag-load); H direct (L2-resident). R7 f0/f1 double buffer,
// identical MFMA order -> bitwise-identical logits.
struct Frags {
  bf16x8 ah[2], al[2], bh[4], bl[4];
};

__device__ inline void load_frags(Frags& f, const unsigned short* wpk,
                                  const unsigned short* hh,
                                  const unsigned short* hl, int kcl) {
  const unsigned short* p = wpk + kcl * 2048;
  f.ah[0] = *(const bf16x8*)(p);
  f.ah[1] = *(const bf16x8*)(p + 512);
  f.al[0] = *(const bf16x8*)(p + 1024);
  f.al[1] = *(const bf16x8*)(p + 1536);
  const int ko = kcl * 32;
#pragma unroll
  for (int bt = 0; bt < 4; ++bt) {
    f.bh[bt] = *(const bf16x8*)(hh + bt * 16 * kH + ko);
    f.bl[bt] = *(const bf16x8*)(hl + bt * 16 * kH + ko);
  }
}

__device__ inline void do_mfma(const Frags& f, f32x4 acc[2][4]) {
#pragma unroll
  for (int tv = 0; tv < 2; ++tv)
#pragma unroll
    for (int bt = 0; bt < 4; ++bt) {
      acc[tv][bt] = __builtin_amdgcn_mfma_f32_16x16x32_bf16(
          f.ah[tv], f.bh[bt], acc[tv][bt], 0, 0, 0);
      acc[tv][bt] = __builtin_amdgcn_mfma_f32_16x16x32_bf16(
          f.ah[tv], f.bl[bt], acc[tv][bt], 0, 0, 0);
      acc[tv][bt] = __builtin_amdgcn_mfma_f32_16x16x32_bf16(
          f.al[tv], f.bh[bt], acc[tv][bt], 0, 0, 0);
    }
}

__global__ __launch_bounds__(512, 2) void logits_mfma_kernel(
    const unsigned short* __restrict__ Wpk,
    const unsigned short* __restrict__ Hhi, const unsigned short* __restrict__ Hlo,
    const float* __restrict__ bout, float* __restrict__ out,
    float* __restrict__ pmax_g, float* __restrict__ psum_g,
    int* __restrict__ pidx_g) {
  const int tid = threadIdx.x;
  const int wave = tid >> 6, lane = tid & 63;
  const int ws = wave & 3;   // v-subtile within block
  const int kh = wave >> 2;  // k-half
  const int m = lane & 15, q = lane >> 4;
  const int v0 = blockIdx.x * 128 + ws * 32;
  const int koff = kh * 512;
  const unsigned short* wpk =
      Wpk + ((size_t)blockIdx.x * 8 + wave) * 32768 + lane * 8;
  const unsigned short* hh = Hhi + (size_t)m * kH + koff + q * 8;
  const unsigned short* hl = Hlo + (size_t)m * kH + koff + q * 8;

  f32x4 acc[2][4];
#pragma unroll
  for (int tv = 0; tv < 2; ++tv)
#pragma unroll
    for (int bt = 0; bt < 4; ++bt) acc[tv][bt] = (f32x4){0.f, 0.f, 0.f, 0.f};

  Frags f0, f1;
  load_frags(f0, wpk, hh, hl, 0);
  // 16 k-chunks of 32 per half, R7's exact double-buffer pattern
  for (int kc2 = 0; kc2 < 16; kc2 += 2) {
    if (kc2 + 1 < 16) load_frags(f1, wpk, hh, hl, kc2 + 1);
    do_mfma(f0, acc);
    if (kc2 + 2 < 16) load_frags(f0, wpk, hh, hl, kc2 + 2);
    do_mfma(f1, acc);
  }

  // ---- combine the two K-halves (padded LDS, lane-contiguous: no conflicts)
  __shared__ float combf[4][32][65];  // 33.3 KB
  if (kh == 1) {
#pragma unroll
    for (int tv = 0; tv < 2; ++tv)
#pragma unroll
      for (int bt = 0; bt < 4; ++bt)
#pragma unroll
        for (int r = 0; r < 4; ++r)
          combf[ws][(tv * 4 + bt) * 4 + r][lane] = acc[tv][bt][r];
  }
  __syncthreads();
  if (kh == 0) {
#pragma unroll
    for (int tv = 0; tv < 2; ++tv)
#pragma unroll
      for (int bt = 0; bt < 4; ++bt)
#pragma unroll
        for (int r = 0; r < 4; ++r)
          acc[tv][bt][r] += combf[ws][(tv * 4 + bt) * 4 + r][lane];
  }

  // bias + store logits (kh==0 waves). D layout: row(v)=q*4+reg, col=lane&15.
  if (kh == 0) {
    float4 bo0 = *(const float4*)(bout + v0 + q * 4);
    float4 bo1 = *(const float4*)(bout + v0 + 16 + q * 4);
#pragma unroll
    for (int tv = 0; tv < 2; ++tv) {
      float4 bo = tv ? bo1 : bo0;
#pragma unroll
      for (int bt = 0; bt < 4; ++bt) {
        int b = bt * 16 + m;
        f32x4 a = acc[tv][bt];
        a[0] += bo.x; a[1] += bo.y; a[2] += bo.z; a[3] += bo.w;
        acc[tv][bt] = a;
        float4 o = make_float4(a[0], a[1], a[2], a[3]);
        *(float4*)(out + (size_t)b * kV + v0 + tv * 16 + q * 4) = o;
      }
    }
  }

  // ---- per-block softmax/argmax partials (layout [b][256]); barriers are
  // block-wide (all 512 threads), work guarded to kh==0.
  __shared__ float lred[4][4][64];
  __shared__ int lidx[4][4][64];
  __shared__ float bbm[64];
  const int blk = blockIdx.x;
  const int vbase = blk * 128;

  if (kh == 0) {
#pragma unroll
    for (int bt = 0; bt < 4; ++bt) {
      float pmv = -INFINITY;
      int piv = 0x7fffffff;
#pragma unroll
      for (int tv = 0; tv < 2; ++tv)
#pragma unroll
        for (int r = 0; r < 4; ++r) {
          float val = acc[tv][bt][r];
          int v = vbase + ws * 32 + tv * 16 + q * 4 + r;
          if (val > pmv) { pmv = val; piv = v; }  // strict >, v ascending
        }
      lred[ws][q][bt * 16 + m] = pmv;
      lidx[ws][q][bt * 16 + m] = piv;
    }
  }
  __syncthreads();
  if (tid < 64) {
    float bm = -INFINITY;
    int bi = 0x7fffffff;
#pragma unroll
    for (int w = 0; w < 4; ++w)
#pragma unroll
      for (int qq = 0; qq < 4; ++qq) {
        float v2 = lred[w][qq][tid];
        int i2 = lidx[w][qq][tid];
        if (v2 > bm || (v2 == bm && i2 < bi)) { bm = v2; bi = i2; }
      }
    bbm[tid] = bm;
    pmax_g[(size_t)tid * 256 + blk] = bm;
    pidx_g[(size_t)tid * 256 + blk] = bi;
  }
  __syncthreads();
  if (kh == 0) {
#pragma unroll
    for (int bt = 0; bt < 4; ++bt) {
      float bm = bbm[bt * 16 + m];
      float s = 0.f;
#pragma unroll
      for (int tv = 0; tv < 2; ++tv)
#pragma unroll
        for (int r = 0; r < 4; ++r) s += expf(acc[tv][bt][r] - bm);
      lred[ws][q][bt * 16 + m] = s;
    }
  }
  __syncthreads();
  if (tid < 64) {
    float s = 0.f;
#pragma unroll
    for (int w = 0; w < 4; ++w)
#pragma unroll
      for (int qq = 0; qq < 4; ++qq) s += lred[w][qq][tid];
    psum_g[(size_t)tid * 256 + blk] = s;
  }
}

// ----------------------------------------------- finalize: reduce partials --
// grid 64 (one block per b): global max/argmax/sum from 250 partials, mask,
// and x_next = E[argmax] gather. (R1-verified.)
__global__ __launch_bounds__(256) void finalize_kernel(
    const float* __restrict__ pm, const float* __restrict__ ps,
    const int* __restrict__ pig, const float* __restrict__ out_t,
    const float* __restrict__ E, float* __restrict__ x,
    float* __restrict__ mask) {
  __shared__ float sm[256];
  __shared__ int si[256];
  __shared__ float ss[256];
  const int b = blockIdx.x, tid = threadIdx.x;
  float m = -INFINITY;
  int idx = 0x7fffffff;
  if (tid < 250) {
    m = pm[(size_t)b * 256 + tid];
    idx = pig[(size_t)b * 256 + tid];
  }
  sm[tid] = m;
  si[tid] = idx;
  __syncthreads();
  for (int off = 128; off > 0; off >>= 1) {
    if (tid < off) {
      float o = sm[tid + off];
      int oi = si[tid + off];
      if (o > sm[tid] || (o == sm[tid] && oi < si[tid])) {
        sm[tid] = o;
        si[tid] = oi;
      }
    }
    __syncthreads();
  }
  const float M = sm[0];
  const int amax = si[0];
  float term = 0.f;
  if (tid < 250) term = ps[(size_t)b * 256 + tid] * expf(m - M);
  ss[tid] = term;
  __syncthreads();
  for (int off = 128; off > 0; off >>= 1) {
    if (tid < off) ss[tid] += ss[tid + off];
    __syncthreads();
  }
  if (tid == 0) mask[b] = expf(out_t[(size_t)b * kV + kEOS] - M) / ss[0];
  for (int u = tid; u < kH; u += 256)
    x[u * 64 + b] = E[(size_t)amax * kH + u];
}

// -------------------------------------------------------------- launch ------
extern "C" void kernel_launch(void* const* d_in, const int* in_sizes, int n_in,
                              void* d_out, int out_size, void* d_ws,
                              size_t ws_size, hipStream_t stream) {
  const float* E = (const float*)d_in[0];
  const float* Wih = (const float*)d_in[1];
  const float* Whh = (const float*)d_in[2];
  const float* bih = (const float*)d_in[3];
  const float* bhh = (const float*)d_in[4];
  const float* Wout = (const float*)d_in[5];
  const float* bout = (const float*)d_in[6];
  const float* eh = (const float*)d_in[7];
  const float* ec = (const float*)d_in[8];
  float* out = (float*)d_out;
  float* ws = (float*)d_ws;

  float* x = ws;
  float* h = ws + 65536;
  float* c = ws + 131072;
  float* part = ws + 196608;
  float* pmaxg = ws + 2293760;
  float* psumg = ws + 2310144;
  int* pidxg = (int*)(ws + 2326528);
  unsigned short* Wpk = (unsigned short*)(ws + 2359296);
  unsigned short* Hhi = Wpk + (size_t)2 * kV * kH;
  unsigned short* Hlo = Hhi + (size_t)kB * kH;

  init_kernel<<<256, 256, 0, stream>>>(E, eh, ec, ws);
  wsplit_pack_kernel<<<2000, 256, 0, stream>>>(Wout, Wpk);
  for (int t = 0; t < kT; ++t) {
    float* out_t = out + (size_t)t * kB * kV;
    gates_kernel<<<dim3(64, 8), 256, 0, stream>>>(Wih, Whh, x, h, part);
    lstm_kernel<<<256, 256, 0, stream>>>(part, bih, bhh, h, c, Hhi, Hlo);
    logits_mfma_kernel<<<250, 512, 0, stream>>>(
        Wpk, Hhi, Hlo, bout, out_t, pmaxg, psumg, pidxg);
    finalize_kernel<<<64, 256, 0, stream>>>(pmaxg, psumg, pidxg, out_t, E, x,
                                            out + (size_t)kT * kB * kV + t * kB);
  }
}